// Round 10
// baseline (277.827 us; speedup 1.0000x reference)
//
#include <hip/hip_runtime.h>
#include <hip/hip_bf16.h>

typedef __attribute__((ext_vector_type(4))) float f32x4;
typedef __attribute__((ext_vector_type(16))) float f32x16;
typedef __attribute__((ext_vector_type(8))) short s16x8;
typedef unsigned int u32;

#define DEVINL static __device__ __forceinline__

constexpr int TDIM = 4096;
constexpr int DDIM = 128;
// softmax logit scale folded into Q' projection: log2(e) / sqrt(T)
constexpr float QSCALE = 1.4426950408889634f / 64.0f;

DEVINL unsigned short f2bf(float f) {
  union { float f; unsigned u; } v; v.f = f;
  unsigned r = v.u + 0x7fffu + ((v.u >> 16) & 1u);
  return (unsigned short)(r >> 16);
}

// ---------------- kernel 0: M = Wq Wk^T (bf16, B-frag layout), u = Wk bq ----
// S[t,s] = (h_t M + u)·h_s + rowconst(t) + const; rowconst cancels in softmax.
__global__ __launch_bounds__(256) void prep_kernel(
    const float* __restrict__ Wq, const float* __restrict__ Wk,
    const float* __restrict__ bq, unsigned short* __restrict__ Mt,
    float* __restrict__ u) {
  int idx = blockIdx.x * 256 + threadIdx.x;  // 16384 entries
  int e = idx >> 7, d = idx & 127;
  float acc = 0.f;
#pragma unroll 4
  for (int h = 0; h < 128; ++h) acc += Wq[d * 128 + h] * Wk[e * 128 + h];
  Mt[e * 128 + d] = f2bf(acc);  // Mt[e][d] = M[d][e]
  if (blockIdx.x == 0 && threadIdx.x < 128) {
    float a = 0.f;
#pragma unroll 4
    for (int h = 0; h < 128; ++h) a += Wk[threadIdx.x * 128 + h] * bq[h];
    u[threadIdx.x] = a;
  }
}

// ---------------- kernel 1: Q' projection + H transcodes ----------------
// Layouts (swizzle baked into global, G21 both-sides):
//   Qb[t][.]: byte = t*256 + ((e*2) ^ ((t&15)<<4))
//   Kb[r][.]: byte = r*256 + ((d*2) ^ ((r&15)<<4))           (bf16 H rows)
//   Vt: per 32-kv tile (8 KB), 256B rows rq=d>>2 (<=2-way banks):
//       byte = rq*256 + (((d&3)*64 + tl*2) ^ ((rq&15)<<4)), tl = kv&31
__global__ __launch_bounds__(256) void proj_kernel(
    const float* __restrict__ H, const unsigned short* __restrict__ Mt,
    const float* __restrict__ u, char* __restrict__ Qb,
    char* __restrict__ Kb, char* __restrict__ Vt) {
  __shared__ __align__(16) unsigned short hs[64][136];
  __shared__ __align__(16) char qs[16384];
  __shared__ __align__(16) char kt[16384];
  __shared__ __align__(16) char vt[16384];
  int b = blockIdx.x;
  int n = b >> 6;
  int t0 = (b & 63) << 6;
  int tid = threadIdx.x;
  const float* Hrow = H + (size_t)(n * TDIM + t0) * DDIM;
#pragma unroll
  for (int k = 0; k < 8; ++k) {
    int e = tid + k * 256;
    int r = e >> 5;            // t-local 0..63
    int c = (e & 31) << 2;     // d 0..124
    f32x4 v = *(const f32x4*)(Hrow + r * DDIM + c);
    unsigned short bf[4] = {f2bf(v.x), f2bf(v.y), f2bf(v.z), f2bf(v.w)};
    unsigned short* p = &hs[r][c];
    p[0] = bf[0]; p[1] = bf[1]; p[2] = bf[2]; p[3] = bf[3];
    // Kb tile: 8B block survives the 16B-granule XOR intact
    int kbyte = r * 256 + ((c * 2) ^ ((r & 15) << 4));
    unsigned short* kp = (unsigned short*)(kt + kbyte);
    kp[0] = bf[0]; kp[1] = bf[1]; kp[2] = bf[2]; kp[3] = bf[3];
    // Vt 256B-row tiles (2 per block: r>>5)
    int p32 = r >> 5, tl = r & 31;
#pragma unroll
    for (int j = 0; j < 4; ++j) {
      int d = c + j;
      int rq = d >> 2;
      int byte = p32 * 8192 + rq * 256 +
                 (((d & 3) * 64 + tl * 2) ^ ((rq & 15) << 4));
      *(unsigned short*)(vt + byte) = bf[j];
    }
  }
  __syncthreads();
  int w = tid >> 6, ln = tid & 63;
  int lm = ln & 15, lg = ln >> 4;
  int m0 = w * 16;
  s16x8 af[4];
#pragma unroll
  for (int kf = 0; kf < 4; ++kf)
    af[kf] = *(const s16x8*)&hs[m0 + lm][kf * 32 + lg * 8];
  // Q' = H M + u, scaled by QSCALE
#pragma unroll
  for (int nt = 0; nt < 8; ++nt) {
    f32x4 acc = {0.f, 0.f, 0.f, 0.f};
#pragma unroll
    for (int kf = 0; kf < 4; ++kf) {
      s16x8 bfr = *(const s16x8*)&Mt[(nt * 16 + lm) * 128 + kf * 32 + lg * 8];
      acc = __builtin_amdgcn_mfma_f32_16x16x32_bf16(af[kf], bfr, acc, 0, 0, 0);
    }
    int e = nt * 16 + lm;
    float bv = u[e];
#pragma unroll
    for (int i = 0; i < 4; ++i) {
      int tl = m0 + lg * 4 + i;
      int byte = tl * 256 + ((e * 2) ^ ((tl & 15) << 4));
      *(unsigned short*)(qs + byte) = f2bf((acc[i] + bv) * QSCALE);
    }
  }
  __syncthreads();
  // coalesced flush: 16KB each, b128
  size_t base = (size_t)(n * TDIM + t0) * 256;
  size_t vbase = (size_t)(n * 128 + (t0 >> 5)) * 8192;
#pragma unroll
  for (int k = 0; k < 4; ++k) {
    int off = tid * 16 + k * 4096;
    *(f32x4*)(Qb + base + off) = *(const f32x4*)(qs + off);
    *(f32x4*)(Kb + base + off) = *(const f32x4*)(kt + off);
    *(f32x4*)(Vt + vbase + off) = *(const f32x4*)(vt + off);
  }
}

// async global -> LDS, 4 KiB per wave
DEVINL void stage4(const char* g, char* s, int ln) {
#pragma unroll
  for (int j = 0; j < 4; ++j) {
    __builtin_amdgcn_global_load_lds(
        (const __attribute__((address_space(1))) void*)(g + j * 1024 + ln * 16),
        (__attribute__((address_space(3))) void*)(s + j * 1024), 16, 0, 0);
  }
}

// ---------------- kernel 2: flash attention partials ----------------
// 1024 blocks x 256 thr (4 waves x 32 q). Block = (batch, kv-stream/4, q-tile).
// KVBLK=32 -> 32KB LDS -> 4 blocks/CU; VGPR<=128 via launch_bounds(256,4)
// -> 16 waves/CU = 4 waves/SIMD (2x R8). QK accumulator SPLIT into two
// 4-deep chains (s_a d0-3, s_b d4-7): 8 independent MFMA chains/SIMD vs 4 --
// attacks the MFMA dep-latency wall (R4/R8/R9 invariant 35% MfmaUtil).
// No-max softmax; in-register P (T12). Packed bf16 partials (R9 scheme):
// streams 0,1 share d_out rows (u32[0..63]/[64..127]), streams 2,3 in ws.
__global__ __launch_bounds__(256, 4) void attn_kernel(
    const char* __restrict__ Qsw, const char* __restrict__ Ksw,
    const char* __restrict__ Vsw, u32* __restrict__ OutU,
    u32* __restrict__ OpU, float* __restrict__ Lp) {
  __shared__ __align__(16) char kbuf[2][8192];
  __shared__ __align__(16) char vbuf[2][8192];
  int b = blockIdx.x;
  int n = b & 7;               // batch per XCD: tiles L2-resident
  int st = (b >> 3) & 3;       // kv stream (1024 kv each)
  int q0 = (b >> 5) << 7;      // 32 q-tiles of 128
  int tid = threadIdx.x;
  int w = tid >> 6, ln = tid & 63;
  int q32 = ln & 31, hi = ln >> 5;
  int qrow = q0 + w * 32;
  int swz = (q32 & 15) << 4;

  const char* Kn = Ksw + (size_t)n * (TDIM * 256);
  const char* Vn = Vsw + (size_t)n * (128 * 8192);
  int kv0 = st * 1024;

  // Q' fragments (global rows XOR-swizzled)
  const char* Qn = Qsw + (size_t)(n * TDIM + qrow + q32) * 256;
  s16x8 qf[8];
#pragma unroll
  for (int d = 0; d < 8; ++d)
    qf[d] = *(const s16x8*)(Qn + ((d * 32 + hi * 16) ^ swz));

  f32x16 o[4];
#pragma unroll
  for (int dt = 0; dt < 4; ++dt) o[dt] = (f32x16)0.0f;
  float lsum = 0.f;

  // staging: waves 0,1 -> K tile halves; waves 2,3 -> V tile halves (4KB each)
  {
    const char* g = (w < 2)
        ? (Kn + (size_t)kv0 * 256 + w * 4096)
        : (Vn + (size_t)(kv0 >> 5) * 8192 + (w - 2) * 4096);
    char* dst = (w < 2) ? (kbuf[0] + w * 4096) : (vbuf[0] + (w - 2) * 4096);
    stage4(g, dst, ln);
  }
  __syncthreads();

  for (int it = 0; it < 32; ++it) {
    int c = it & 1;
    if (it < 31) {
      int kvn = kv0 + (it + 1) * 32;
      const char* g = (w < 2)
          ? (Kn + (size_t)kvn * 256 + w * 4096)
          : (Vn + (size_t)(kvn >> 5) * 8192 + (w - 2) * 4096);
      char* dst = (w < 2) ? (kbuf[c ^ 1] + w * 4096)
                          : (vbuf[c ^ 1] + (w - 2) * 4096);
      stage4(g, dst, ln);
    }
    const char* kb = kbuf[c];
    const char* vb = vbuf[c];

    // QK^T swapped, SPLIT accumulators: s_a over d0-3, s_b over d4-7
    // (two independent 4-deep chains instead of one 8-deep chain)
    f32x16 sa = (f32x16)0.0f, sb = (f32x16)0.0f;
    __builtin_amdgcn_s_setprio(1);
#pragma unroll
    for (int d = 0; d < 4; ++d) {
      s16x8 ka0 = *(const s16x8*)(kb + (q32 * 256 + ((d * 32 + hi * 16) ^ swz)));
      s16x8 ka1 = *(const s16x8*)(kb + (q32 * 256 + (((d + 4) * 32 + hi * 16) ^ swz)));
      sa = __builtin_amdgcn_mfma_f32_32x32x16_bf16(ka0, qf[d], sa, 0, 0, 0);
      sb = __builtin_amdgcn_mfma_f32_32x32x16_bf16(ka1, qf[d + 4], sb, 0, 0, 0);
    }
    __builtin_amdgcn_s_setprio(0);

    // softmax numerator: plain exp2 (no max: |logit| bounded tiny)
    f32x16 p0;
    float ls = 0.f;
#pragma unroll
    for (int r = 0; r < 16; ++r) {
      p0[r] = __builtin_amdgcn_exp2f(sa[r] + sb[r]);
      ls += p0[r];
    }
    lsum += ls;

    // pack P -> A-fragments in-register (T12)
    s16x8 pa[2];
    {
      u32 P2[8];
#pragma unroll
      for (int r = 0; r < 8; ++r)
        asm("v_cvt_pk_bf16_f32 %0, %1, %2"
            : "=v"(P2[r]) : "v"(p0[2 * r]), "v"(p0[2 * r + 1]));
#pragma unroll
      for (int b2 = 0; b2 < 2; ++b2) {
        u32 a0 = P2[b2 * 4 + 0], c0 = P2[b2 * 4 + 2];
        u32 a1 = P2[b2 * 4 + 1], c1 = P2[b2 * 4 + 3];
        asm("v_permlane32_swap_b32 %0, %1" : "+v"(a0), "+v"(c0));
        asm("v_permlane32_swap_b32 %0, %1" : "+v"(a1), "+v"(c1));
        union { u32 u[4]; s16x8 v; } pk;
        pk.u[0] = a0; pk.u[1] = a1; pk.u[2] = c0; pk.u[3] = c1;
        pa[b2] = pk.v;
      }
    }

    // PV: 4 independent 2-deep chains (dt), V from 256B-row LDS tiles
    __builtin_amdgcn_s_setprio(1);
#pragma unroll
    for (int ks = 0; ks < 2; ++ks) {
#pragma unroll
      for (int dt = 0; dt < 4; ++dt) {
        int rq = dt * 8 + (q32 >> 2);
        s16x8 vv = *(const s16x8*)(vb + rq * 256 +
            (((q32 & 3) * 64 + ks * 32 + hi * 16) ^ ((rq & 15) << 4)));
        o[dt] = __builtin_amdgcn_mfma_f32_32x32x16_bf16(pa[ks], vv, o[dt], 0, 0, 0);
      }
    }
    __builtin_amdgcn_s_setprio(0);
    __syncthreads();  // 4-wave dbuf handoff
  }

  // epilogue: packed bf16 partial O (R9 scheme). Row slot = 128 u32:
  // stream-even at u32[0..63], stream-odd at u32[64..127];
  // slot q32 holds (d=q32, d=32+q32), slot 32+q32 holds (d=64+q32, d=96+q32).
  u32* Ob = (st < 2 ? OutU : OpU) + (st & 1) * 64;
#pragma unroll
  for (int r = 0; r < 16; ++r) {
    int qr = (r & 3) + 8 * (r >> 2) + 4 * hi;
    size_t rl = (size_t)(n * TDIM + qrow + qr) * 128;
    u32 a, bb;
    asm("v_cvt_pk_bf16_f32 %0, %1, %2" : "=v"(a) : "v"(o[0][r]), "v"(o[1][r]));
    asm("v_cvt_pk_bf16_f32 %0, %1, %2" : "=v"(bb) : "v"(o[2][r]), "v"(o[3][r]));
    Ob[rl + q32] = a;
    Ob[rl + 32 + q32] = bb;
  }
  Lp[(size_t)(n * TDIM + qrow + q32) * 8 + st * 2 + hi] = lsum;
}

// ---------------- kernel 3: merge packed partials + residual ----------------
// thread (row, pi): unpack 4 streams' bf16 pairs, /Σl, +H, write f32.
// Row's 64 threads are one wave -> lockstep loads precede stores (safe RMW).
__global__ __launch_bounds__(256) void merge_kernel(
    u32* __restrict__ OutU, const u32* __restrict__ OpU,
    const float* __restrict__ Lp, const float* __restrict__ H) {
  int gid = blockIdx.x * 256 + threadIdx.x;
  int row = gid >> 6;
  int pi = gid & 63;
  int q32 = pi & 31, k = pi >> 5;
  f32x4 la = *(const f32x4*)(Lp + (size_t)row * 8);
  f32x4 lb = *(const f32x4*)(Lp + (size_t)row * 8 + 4);
  float il = 1.0f / (la.x + la.y + la.z + la.w + lb.x + lb.y + lb.z + lb.w);
  size_t rb = (size_t)row * 128;
  u32 p0 = OutU[rb + pi], p1 = OutU[rb + 64 + pi];
  u32 p2 = OpU[rb + pi],  p3 = OpU[rb + 64 + pi];
#define BL(x) __builtin_bit_cast(float, (u32)((x) << 16))
#define BH(x) __builtin_bit_cast(float, (u32)((x) & 0xffff0000u))
  float slo = BL(p0) + BL(p1) + BL(p2) + BL(p3);
  float shi = BH(p0) + BH(p1) + BH(p2) + BH(p3);
#undef BL
#undef BH
  int d0 = k * 64 + q32, d1 = d0 + 32;
  float* Outf = (float*)OutU;
  Outf[rb + d0] = slo * il + H[rb + d0];
  Outf[rb + d1] = shi * il + H[rb + d1];
}

extern "C" void kernel_launch(void* const* d_in, const int* in_sizes, int n_in,
                              void* d_out, int out_size, void* d_ws, size_t ws_size,
                              hipStream_t stream) {
  const float* H  = (const float*)d_in[0];
  const float* Wq = (const float*)d_in[1];
  const float* bq = (const float*)d_in[2];
  const float* Wk = (const float*)d_in[3];
  const float* bk = (const float*)d_in[4];
  (void)bk;  // bk adds only a row-constant logit term (softmax-invariant)
  u32* OutU = (u32*)d_out;
  char* ws = (char*)d_ws;
  unsigned short* Mt = (unsigned short*)(ws);
  float* u = (float*)(ws + 32768);
  char* Qb = ws + 65536;
  char* Kb = Qb + 8388608;
  char* Vt = Kb + 8388608;
  u32* OpU = (u32*)(Vt + 8388608);   // streams 2,3 packed partials (16MB)
  float* Lp = (float*)(ws + 65536 + 3 * 8388608 + 16777216);  // 1MB

  prep_kernel<<<64, 256, 0, stream>>>(Wq, Wk, bq, Mt, u);
  proj_kernel<<<512, 256, 0, stream>>>(H, Mt, u, Qb, Kb, Vt);
  attn_kernel<<<1024, 256, 0, stream>>>(Qb, Kb, Vt, OutU, OpU, Lp);
  merge_kernel<<<8192, 256, 0, stream>>>(OutU, OpU, Lp, H);
}

// Round 11
// 114.283 us; speedup vs baseline: 2.4310x; 2.4310x over previous
//
#include <hip/hip_runtime.h>
#include <hip/hip_bf16.h>

typedef __attribute__((ext_vector_type(4))) float f32x4;
typedef __attribute__((ext_vector_type(16))) float f32x16;
typedef __attribute__((ext_vector_type(8))) short s16x8;
typedef unsigned int u32;

#define DEVINL static __device__ __forceinline__

constexpr int TDIM = 4096;
constexpr int DDIM = 128;
// softmax logit scale folded into Q' projection: log2(e) / sqrt(T)
constexpr float QSCALE = 1.4426950408889634f / 64.0f;

DEVINL unsigned short f2bf(float f) {
  union { float f; unsigned u; } v; v.f = f;
  unsigned r = v.u + 0x7fffu + ((v.u >> 16) & 1u);
  return (unsigned short)(r >> 16);
}

// ---------------- kernel 0: M = Wq Wk^T (bf16, B-frag layout), u = Wk bq ----
// S[t,s] = (h_t M + u)·h_s + rowconst(t) + const; rowconst cancels in softmax.
__global__ __launch_bounds__(256) void prep_kernel(
    const float* __restrict__ Wq, const float* __restrict__ Wk,
    const float* __restrict__ bq, unsigned short* __restrict__ Mt,
    float* __restrict__ u) {
  int idx = blockIdx.x * 256 + threadIdx.x;  // 16384 entries
  int e = idx >> 7, d = idx & 127;
  float acc = 0.f;
#pragma unroll 4
  for (int h = 0; h < 128; ++h) acc += Wq[d * 128 + h] * Wk[e * 128 + h];
  Mt[e * 128 + d] = f2bf(acc);  // Mt[e][d] = M[d][e]
  if (blockIdx.x == 0 && threadIdx.x < 128) {
    float a = 0.f;
#pragma unroll 4
    for (int h = 0; h < 128; ++h) a += Wk[threadIdx.x * 128 + h] * bq[h];
    u[threadIdx.x] = a;
  }
}

// ---------------- kernel 1: Q' projection + H transcodes ----------------
// Layouts (swizzle baked into global, G21 both-sides):
//   Qb[t][.]: byte = t*256 + ((e*2) ^ ((t&15)<<4))
//   Kb[r][.]: byte = r*256 + ((d*2) ^ ((r&15)<<4))           (bf16 H rows)
//   Vt: per 32-kv tile (8 KB), 256B rows rq=d>>2 (<=2-way banks):
//       byte = rq*256 + (((d&3)*64 + tl*2) ^ ((rq&15)<<4)), tl = kv&31
__global__ __launch_bounds__(256) void proj_kernel(
    const float* __restrict__ H, const unsigned short* __restrict__ Mt,
    const float* __restrict__ u, char* __restrict__ Qb,
    char* __restrict__ Kb, char* __restrict__ Vt) {
  __shared__ __align__(16) unsigned short hs[64][136];
  __shared__ __align__(16) char qs[16384];
  __shared__ __align__(16) char kt[16384];
  __shared__ __align__(16) char vt[16384];
  int b = blockIdx.x;
  int n = b >> 6;
  int t0 = (b & 63) << 6;
  int tid = threadIdx.x;
  const float* Hrow = H + (size_t)(n * TDIM + t0) * DDIM;
#pragma unroll
  for (int k = 0; k < 8; ++k) {
    int e = tid + k * 256;
    int r = e >> 5;            // t-local 0..63
    int c = (e & 31) << 2;     // d 0..124
    f32x4 v = *(const f32x4*)(Hrow + r * DDIM + c);
    unsigned short bf[4] = {f2bf(v.x), f2bf(v.y), f2bf(v.z), f2bf(v.w)};
    unsigned short* p = &hs[r][c];
    p[0] = bf[0]; p[1] = bf[1]; p[2] = bf[2]; p[3] = bf[3];
    // Kb tile: 8B block survives the 16B-granule XOR intact
    int kbyte = r * 256 + ((c * 2) ^ ((r & 15) << 4));
    unsigned short* kp = (unsigned short*)(kt + kbyte);
    kp[0] = bf[0]; kp[1] = bf[1]; kp[2] = bf[2]; kp[3] = bf[3];
    // Vt 256B-row tiles (2 per block: r>>5)
    int p32 = r >> 5, tl = r & 31;
#pragma unroll
    for (int j = 0; j < 4; ++j) {
      int d = c + j;
      int rq = d >> 2;
      int byte = p32 * 8192 + rq * 256 +
                 (((d & 3) * 64 + tl * 2) ^ ((rq & 15) << 4));
      *(unsigned short*)(vt + byte) = bf[j];
    }
  }
  __syncthreads();
  int w = tid >> 6, ln = tid & 63;
  int lm = ln & 15, lg = ln >> 4;
  int m0 = w * 16;
  s16x8 af[4];
#pragma unroll
  for (int kf = 0; kf < 4; ++kf)
    af[kf] = *(const s16x8*)&hs[m0 + lm][kf * 32 + lg * 8];
  // Q' = H M + u, scaled by QSCALE
#pragma unroll
  for (int nt = 0; nt < 8; ++nt) {
    f32x4 acc = {0.f, 0.f, 0.f, 0.f};
#pragma unroll
    for (int kf = 0; kf < 4; ++kf) {
      s16x8 bfr = *(const s16x8*)&Mt[(nt * 16 + lm) * 128 + kf * 32 + lg * 8];
      acc = __builtin_amdgcn_mfma_f32_16x16x32_bf16(af[kf], bfr, acc, 0, 0, 0);
    }
    int e = nt * 16 + lm;
    float bv = u[e];
#pragma unroll
    for (int i = 0; i < 4; ++i) {
      int tl = m0 + lg * 4 + i;
      int byte = tl * 256 + ((e * 2) ^ ((tl & 15) << 4));
      *(unsigned short*)(qs + byte) = f2bf((acc[i] + bv) * QSCALE);
    }
  }
  __syncthreads();
  // coalesced flush: 16KB each, b128
  size_t base = (size_t)(n * TDIM + t0) * 256;
  size_t vbase = (size_t)(n * 128 + (t0 >> 5)) * 8192;
#pragma unroll
  for (int k = 0; k < 4; ++k) {
    int off = tid * 16 + k * 4096;
    *(f32x4*)(Qb + base + off) = *(const f32x4*)(qs + off);
    *(f32x4*)(Kb + base + off) = *(const f32x4*)(kt + off);
    *(f32x4*)(Vt + vbase + off) = *(const f32x4*)(vt + off);
  }
}

// async global -> LDS, 4 KiB per wave
DEVINL void stage4(const char* g, char* s, int ln) {
#pragma unroll
  for (int j = 0; j < 4; ++j) {
    __builtin_amdgcn_global_load_lds(
        (const __attribute__((address_space(1))) void*)(g + j * 1024 + ln * 16),
        (__attribute__((address_space(3))) void*)(s + j * 1024), 16, 0, 0);
  }
}

// ---------------- kernel 2: flash attention partials ----------------
// 1024 blocks x 256 thr (4 waves x 32 q). Block = (batch, kv-stream/4, q-tile).
// KVBLK=32, 32KB LDS, launch_bounds(256,2): full register budget (R10's
// (256,4) forced VGPR->64 + scratch spill, FETCH 729GB -- never again).
// QK accumulator split into two 4-deep chains (sa d0-3, sb d4-7): 8
// independent MFMA chains/SIMD at 2 waves/SIMD. No-max softmax; in-register
// P (T12). Packed bf16 partials: streams 0,1 share d_out rows, 2,3 in ws.
__global__ __launch_bounds__(256, 2) void attn_kernel(
    const char* __restrict__ Qsw, const char* __restrict__ Ksw,
    const char* __restrict__ Vsw, u32* __restrict__ OutU,
    u32* __restrict__ OpU, float* __restrict__ Lp) {
  __shared__ __align__(16) char kbuf[2][8192];
  __shared__ __align__(16) char vbuf[2][8192];
  int b = blockIdx.x;
  int n = b & 7;               // batch per XCD: tiles L2-resident
  int st = (b >> 3) & 3;       // kv stream (1024 kv each)
  int q0 = (b >> 5) << 7;      // 32 q-tiles of 128
  int tid = threadIdx.x;
  int w = tid >> 6, ln = tid & 63;
  int q32 = ln & 31, hi = ln >> 5;
  int qrow = q0 + w * 32;
  int swz = (q32 & 15) << 4;

  const char* Kn = Ksw + (size_t)n * (TDIM * 256);
  const char* Vn = Vsw + (size_t)n * (128 * 8192);
  int kv0 = st * 1024;

  // Q' fragments (global rows XOR-swizzled)
  const char* Qn = Qsw + (size_t)(n * TDIM + qrow + q32) * 256;
  s16x8 qf[8];
#pragma unroll
  for (int d = 0; d < 8; ++d)
    qf[d] = *(const s16x8*)(Qn + ((d * 32 + hi * 16) ^ swz));

  f32x16 o[4];
#pragma unroll
  for (int dt = 0; dt < 4; ++dt) o[dt] = (f32x16)0.0f;
  float lsum = 0.f;

  // staging: waves 0,1 -> K tile halves; waves 2,3 -> V tile halves (4KB each)
  {
    const char* g = (w < 2)
        ? (Kn + (size_t)kv0 * 256 + w * 4096)
        : (Vn + (size_t)(kv0 >> 5) * 8192 + (w - 2) * 4096);
    char* dst = (w < 2) ? (kbuf[0] + w * 4096) : (vbuf[0] + (w - 2) * 4096);
    stage4(g, dst, ln);
  }
  __syncthreads();

  for (int it = 0; it < 32; ++it) {
    int c = it & 1;
    if (it < 31) {
      int kvn = kv0 + (it + 1) * 32;
      const char* g = (w < 2)
          ? (Kn + (size_t)kvn * 256 + w * 4096)
          : (Vn + (size_t)(kvn >> 5) * 8192 + (w - 2) * 4096);
      char* dst = (w < 2) ? (kbuf[c ^ 1] + w * 4096)
                          : (vbuf[c ^ 1] + (w - 2) * 4096);
      stage4(g, dst, ln);
    }
    const char* kb = kbuf[c];
    const char* vb = vbuf[c];

    // QK^T swapped, SPLIT accumulators: sa over d0-3, sb over d4-7
    f32x16 sa = (f32x16)0.0f, sb = (f32x16)0.0f;
    __builtin_amdgcn_s_setprio(1);
#pragma unroll
    for (int d = 0; d < 4; ++d) {
      s16x8 ka0 = *(const s16x8*)(kb + (q32 * 256 + ((d * 32 + hi * 16) ^ swz)));
      s16x8 ka1 = *(const s16x8*)(kb + (q32 * 256 + (((d + 4) * 32 + hi * 16) ^ swz)));
      sa = __builtin_amdgcn_mfma_f32_32x32x16_bf16(ka0, qf[d], sa, 0, 0, 0);
      sb = __builtin_amdgcn_mfma_f32_32x32x16_bf16(ka1, qf[d + 4], sb, 0, 0, 0);
    }
    __builtin_amdgcn_s_setprio(0);

    // softmax numerator: plain exp2 (no max: |logit| bounded tiny)
    f32x16 p0;
    float ls = 0.f;
#pragma unroll
    for (int r = 0; r < 16; ++r) {
      p0[r] = __builtin_amdgcn_exp2f(sa[r] + sb[r]);
      ls += p0[r];
    }
    lsum += ls;

    // pack P -> A-fragments in-register (T12)
    s16x8 pa[2];
    {
      u32 P2[8];
#pragma unroll
      for (int r = 0; r < 8; ++r)
        asm("v_cvt_pk_bf16_f32 %0, %1, %2"
            : "=v"(P2[r]) : "v"(p0[2 * r]), "v"(p0[2 * r + 1]));
#pragma unroll
      for (int b2 = 0; b2 < 2; ++b2) {
        u32 a0 = P2[b2 * 4 + 0], c0 = P2[b2 * 4 + 2];
        u32 a1 = P2[b2 * 4 + 1], c1 = P2[b2 * 4 + 3];
        asm("v_permlane32_swap_b32 %0, %1" : "+v"(a0), "+v"(c0));
        asm("v_permlane32_swap_b32 %0, %1" : "+v"(a1), "+v"(c1));
        union { u32 u[4]; s16x8 v; } pk;
        pk.u[0] = a0; pk.u[1] = a1; pk.u[2] = c0; pk.u[3] = c1;
        pa[b2] = pk.v;
      }
    }

    // PV: 4 independent 2-deep chains (dt), V from 256B-row LDS tiles
    __builtin_amdgcn_s_setprio(1);
#pragma unroll
    for (int ks = 0; ks < 2; ++ks) {
#pragma unroll
      for (int dt = 0; dt < 4; ++dt) {
        int rq = dt * 8 + (q32 >> 2);
        s16x8 vv = *(const s16x8*)(vb + rq * 256 +
            (((q32 & 3) * 64 + ks * 32 + hi * 16) ^ ((rq & 15) << 4)));
        o[dt] = __builtin_amdgcn_mfma_f32_32x32x16_bf16(pa[ks], vv, o[dt], 0, 0, 0);
      }
    }
    __builtin_amdgcn_s_setprio(0);
    __syncthreads();  // 4-wave dbuf handoff
  }

  // epilogue: packed bf16 partial O. Row slot = 128 u32:
  // stream-even at u32[0..63], stream-odd at u32[64..127];
  // slot q32 holds (d=q32, d=32+q32), slot 32+q32 holds (d=64+q32, d=96+q32).
  u32* Ob = (st < 2 ? OutU : OpU) + (st & 1) * 64;
#pragma unroll
  for (int r = 0; r < 16; ++r) {
    int qr = (r & 3) + 8 * (r >> 2) + 4 * hi;
    size_t rl = (size_t)(n * TDIM + qrow + qr) * 128;
    u32 a, bb;
    asm("v_cvt_pk_bf16_f32 %0, %1, %2" : "=v"(a) : "v"(o[0][r]), "v"(o[1][r]));
    asm("v_cvt_pk_bf16_f32 %0, %1, %2" : "=v"(bb) : "v"(o[2][r]), "v"(o[3][r]));
    Ob[rl + q32] = a;
    Ob[rl + 32 + q32] = bb;
  }
  Lp[(size_t)(n * TDIM + qrow + q32) * 8 + st * 2 + hi] = lsum;
}

// ---------------- kernel 3: merge packed partials + residual ----------------
// thread (row, pi): unpack 4 streams' bf16 pairs, /Σl, +H, write f32.
// Row's 64 threads are one wave -> lockstep loads precede stores (safe RMW).
__global__ __launch_bounds__(256) void merge_kernel(
    u32* __restrict__ OutU, const u32* __restrict__ OpU,
    const float* __restrict__ Lp, const float* __restrict__ H) {
  int gid = blockIdx.x * 256 + threadIdx.x;
  int row = gid >> 6;
  int pi = gid & 63;
  int q32 = pi & 31, k = pi >> 5;
  f32x4 la = *(const f32x4*)(Lp + (size_t)row * 8);
  f32x4 lb = *(const f32x4*)(Lp + (size_t)row * 8 + 4);
  float il = 1.0f / (la.x + la.y + la.z + la.w + lb.x + lb.y + lb.z + lb.w);
  size_t rb = (size_t)row * 128;
  u32 p0 = OutU[rb + pi], p1 = OutU[rb + 64 + pi];
  u32 p2 = OpU[rb + pi],  p3 = OpU[rb + 64 + pi];
#define BL(x) __builtin_bit_cast(float, (u32)((x) << 16))
#define BH(x) __builtin_bit_cast(float, (u32)((x) & 0xffff0000u))
  float slo = BL(p0) + BL(p1) + BL(p2) + BL(p3);
  float shi = BH(p0) + BH(p1) + BH(p2) + BH(p3);
#undef BL
#undef BH
  int d0 = k * 64 + q32, d1 = d0 + 32;
  float* Outf = (float*)OutU;
  Outf[rb + d0] = slo * il + H[rb + d0];
  Outf[rb + d1] = shi * il + H[rb + d1];
}

extern "C" void kernel_launch(void* const* d_in, const int* in_sizes, int n_in,
                              void* d_out, int out_size, void* d_ws, size_t ws_size,
                              hipStream_t stream) {
  const float* H  = (const float*)d_in[0];
  const float* Wq = (const float*)d_in[1];
  const float* bq = (const float*)d_in[2];
  const float* Wk = (const float*)d_in[3];
  const float* bk = (const float*)d_in[4];
  (void)bk;  // bk adds only a row-constant logit term (softmax-invariant)
  u32* OutU = (u32*)d_out;
  char* ws = (char*)d_ws;
  unsigned short* Mt = (unsigned short*)(ws);
  float* u = (float*)(ws + 32768);
  char* Qb = ws + 65536;
  char* Kb = Qb + 8388608;
  char* Vt = Kb + 8388608;
  u32* OpU = (u32*)(Vt + 8388608);   // streams 2,3 packed partials (16MB)
  float* Lp = (float*)(ws + 65536 + 3 * 8388608 + 16777216);  // 1MB

  prep_kernel<<<64, 256, 0, stream>>>(Wq, Wk, bq, Mt, u);
  proj_kernel<<<512, 256, 0, stream>>>(H, Mt, u, Qb, Kb, Vt);
  attn_kernel<<<1024, 256, 0, stream>>>(Qb, Kb, Vt, OutU, OpU, Lp);
  merge_kernel<<<8192, 256, 0, stream>>>(OutU, OpU, Lp, H);
}

// Round 12
// 110.705 us; speedup vs baseline: 2.5096x; 1.0323x over previous
//
#include <hip/hip_runtime.h>
#include <hip/hip_bf16.h>

typedef __attribute__((ext_vector_type(4))) float f32x4;
typedef __attribute__((ext_vector_type(16))) float f32x16;
typedef __attribute__((ext_vector_type(8))) short s16x8;
typedef unsigned int u32;

#define DEVINL static __device__ __forceinline__

constexpr int TDIM = 4096;
constexpr int DDIM = 128;
// softmax logit scale folded into Q' projection: log2(e) / sqrt(T)
constexpr float QSCALE = 1.4426950408889634f / 64.0f;

DEVINL unsigned short f2bf(float f) {
  union { float f; unsigned u; } v; v.f = f;
  unsigned r = v.u + 0x7fffu + ((v.u >> 16) & 1u);
  return (unsigned short)(r >> 16);
}

// ---------------- kernel 0: M = Wq Wk^T (bf16, B-frag layout), u = Wk bq ----
// S[t,s] = (h_t M + u)·h_s + rowconst(t) + const; rowconst cancels in softmax.
__global__ __launch_bounds__(256) void prep_kernel(
    const float* __restrict__ Wq, const float* __restrict__ Wk,
    const float* __restrict__ bq, unsigned short* __restrict__ Mt,
    float* __restrict__ u) {
  int idx = blockIdx.x * 256 + threadIdx.x;  // 16384 entries
  int e = idx >> 7, d = idx & 127;
  float acc = 0.f;
#pragma unroll 4
  for (int h = 0; h < 128; ++h) acc += Wq[d * 128 + h] * Wk[e * 128 + h];
  Mt[e * 128 + d] = f2bf(acc);  // Mt[e][d] = M[d][e]
  if (blockIdx.x == 0 && threadIdx.x < 128) {
    float a = 0.f;
#pragma unroll 4
    for (int h = 0; h < 128; ++h) a += Wk[threadIdx.x * 128 + h] * bq[h];
    u[threadIdx.x] = a;
  }
}

// ---------------- kernel 1: Q' projection + H transcodes ----------------
// Layouts (swizzle baked into global, G21 both-sides):
//   Qb[t][.]: byte = t*256 + ((e*2) ^ ((t&15)<<4))
//   Kb[r][.]: byte = r*256 + ((d*2) ^ ((r&15)<<4))           (bf16 H rows)
//   Vt: per 32-kv tile (8 KB), 256B rows rq=d>>2 (<=2-way banks):
//       byte = rq*256 + (((d&3)*64 + tl*2) ^ ((rq&15)<<4)), tl = kv&31
__global__ __launch_bounds__(256) void proj_kernel(
    const float* __restrict__ H, const unsigned short* __restrict__ Mt,
    const float* __restrict__ u, char* __restrict__ Qb,
    char* __restrict__ Kb, char* __restrict__ Vt) {
  __shared__ __align__(16) unsigned short hs[64][136];
  __shared__ __align__(16) char qs[16384];
  __shared__ __align__(16) char kt[16384];
  __shared__ __align__(16) char vt[16384];
  int b = blockIdx.x;
  int n = b >> 6;
  int t0 = (b & 63) << 6;
  int tid = threadIdx.x;
  const float* Hrow = H + (size_t)(n * TDIM + t0) * DDIM;
#pragma unroll
  for (int k = 0; k < 8; ++k) {
    int e = tid + k * 256;
    int r = e >> 5;            // t-local 0..63
    int c = (e & 31) << 2;     // d 0..124
    f32x4 v = *(const f32x4*)(Hrow + r * DDIM + c);
    unsigned short bf[4] = {f2bf(v.x), f2bf(v.y), f2bf(v.z), f2bf(v.w)};
    unsigned short* p = &hs[r][c];
    p[0] = bf[0]; p[1] = bf[1]; p[2] = bf[2]; p[3] = bf[3];
    // Kb tile: 8B block survives the 16B-granule XOR intact
    int kbyte = r * 256 + ((c * 2) ^ ((r & 15) << 4));
    unsigned short* kp = (unsigned short*)(kt + kbyte);
    kp[0] = bf[0]; kp[1] = bf[1]; kp[2] = bf[2]; kp[3] = bf[3];
    // Vt 256B-row tiles (2 per block: r>>5)
    int p32 = r >> 5, tl = r & 31;
#pragma unroll
    for (int j = 0; j < 4; ++j) {
      int d = c + j;
      int rq = d >> 2;
      int byte = p32 * 8192 + rq * 256 +
                 (((d & 3) * 64 + tl * 2) ^ ((rq & 15) << 4));
      *(unsigned short*)(vt + byte) = bf[j];
    }
  }
  __syncthreads();
  int w = tid >> 6, ln = tid & 63;
  int lm = ln & 15, lg = ln >> 4;
  int m0 = w * 16;
  s16x8 af[4];
#pragma unroll
  for (int kf = 0; kf < 4; ++kf)
    af[kf] = *(const s16x8*)&hs[m0 + lm][kf * 32 + lg * 8];
  // Q' = H M + u, scaled by QSCALE
#pragma unroll
  for (int nt = 0; nt < 8; ++nt) {
    f32x4 acc = {0.f, 0.f, 0.f, 0.f};
#pragma unroll
    for (int kf = 0; kf < 4; ++kf) {
      s16x8 bfr = *(const s16x8*)&Mt[(nt * 16 + lm) * 128 + kf * 32 + lg * 8];
      acc = __builtin_amdgcn_mfma_f32_16x16x32_bf16(af[kf], bfr, acc, 0, 0, 0);
    }
    int e = nt * 16 + lm;
    float bv = u[e];
#pragma unroll
    for (int i = 0; i < 4; ++i) {
      int tl = m0 + lg * 4 + i;
      int byte = tl * 256 + ((e * 2) ^ ((tl & 15) << 4));
      *(unsigned short*)(qs + byte) = f2bf((acc[i] + bv) * QSCALE);
    }
  }
  __syncthreads();
  // coalesced flush: 16KB each, b128
  size_t base = (size_t)(n * TDIM + t0) * 256;
  size_t vbase = (size_t)(n * 128 + (t0 >> 5)) * 8192;
#pragma unroll
  for (int k = 0; k < 4; ++k) {
    int off = tid * 16 + k * 4096;
    *(f32x4*)(Qb + base + off) = *(const f32x4*)(qs + off);
    *(f32x4*)(Kb + base + off) = *(const f32x4*)(kt + off);
    *(f32x4*)(Vt + vbase + off) = *(const f32x4*)(vt + off);
  }
}

// async global -> LDS, 4 KiB per wave
DEVINL void stage4(const char* g, char* s, int ln) {
#pragma unroll
  for (int j = 0; j < 4; ++j) {
    __builtin_amdgcn_global_load_lds(
        (const __attribute__((address_space(1))) void*)(g + j * 1024 + ln * 16),
        (__attribute__((address_space(3))) void*)(s + j * 1024), 16, 0, 0);
  }
}

// ---------------- kernel 2: flash attention partials ----------------
// 512 blocks x 256 thr (4 waves x 32 q) = (batch, kv-stream/2, q-tile).
// Exactly 2 resident blocks/CU (32KB LDS, ~184 unified regs/wave), zero
// scheduling tail. KVBLK=32, 64 iters. QK split into two 4-deep chains.
// No-max softmax; in-register P (T12). BOTH packed-bf16 partial streams
// live in d_out row slots (stream st at u32[st*64 .. st*64+63]).
__global__ __launch_bounds__(256, 2) void attn_kernel(
    const char* __restrict__ Qsw, const char* __restrict__ Ksw,
    const char* __restrict__ Vsw, u32* __restrict__ OutU,
    float* __restrict__ Lp) {
  __shared__ __align__(16) char kbuf[2][8192];
  __shared__ __align__(16) char vbuf[2][8192];
  int b = blockIdx.x;
  int n = b & 7;               // batch per XCD: tiles L2-resident
  int st = (b >> 3) & 1;       // kv stream (2048 kv each)
  int q0 = (b >> 4) << 7;      // 32 q-tiles of 128
  int tid = threadIdx.x;
  int w = tid >> 6, ln = tid & 63;
  int q32 = ln & 31, hi = ln >> 5;
  int qrow = q0 + w * 32;
  int swz = (q32 & 15) << 4;

  const char* Kn = Ksw + (size_t)n * (TDIM * 256);
  const char* Vn = Vsw + (size_t)n * (128 * 8192);
  int kv0 = st * 2048;

  // Q' fragments (global rows XOR-swizzled)
  const char* Qn = Qsw + (size_t)(n * TDIM + qrow + q32) * 256;
  s16x8 qf[8];
#pragma unroll
  for (int d = 0; d < 8; ++d)
    qf[d] = *(const s16x8*)(Qn + ((d * 32 + hi * 16) ^ swz));

  f32x16 o[4];
#pragma unroll
  for (int dt = 0; dt < 4; ++dt) o[dt] = (f32x16)0.0f;
  float lsum = 0.f;

  // staging: waves 0,1 -> K tile halves; waves 2,3 -> V tile halves (4KB each)
  {
    const char* g = (w < 2)
        ? (Kn + (size_t)kv0 * 256 + w * 4096)
        : (Vn + (size_t)(kv0 >> 5) * 8192 + (w - 2) * 4096);
    char* dst = (w < 2) ? (kbuf[0] + w * 4096) : (vbuf[0] + (w - 2) * 4096);
    stage4(g, dst, ln);
  }
  __syncthreads();

  for (int it = 0; it < 64; ++it) {
    int c = it & 1;
    if (it < 63) {
      int kvn = kv0 + (it + 1) * 32;
      const char* g = (w < 2)
          ? (Kn + (size_t)kvn * 256 + w * 4096)
          : (Vn + (size_t)(kvn >> 5) * 8192 + (w - 2) * 4096);
      char* dst = (w < 2) ? (kbuf[c ^ 1] + w * 4096)
                          : (vbuf[c ^ 1] + (w - 2) * 4096);
      stage4(g, dst, ln);
    }
    const char* kb = kbuf[c];
    const char* vb = vbuf[c];

    // QK^T swapped, SPLIT accumulators: sa over d0-3, sb over d4-7
    f32x16 sa = (f32x16)0.0f, sb = (f32x16)0.0f;
    __builtin_amdgcn_s_setprio(1);
#pragma unroll
    for (int d = 0; d < 4; ++d) {
      s16x8 ka0 = *(const s16x8*)(kb + (q32 * 256 + ((d * 32 + hi * 16) ^ swz)));
      s16x8 ka1 = *(const s16x8*)(kb + (q32 * 256 + (((d + 4) * 32 + hi * 16) ^ swz)));
      sa = __builtin_amdgcn_mfma_f32_32x32x16_bf16(ka0, qf[d], sa, 0, 0, 0);
      sb = __builtin_amdgcn_mfma_f32_32x32x16_bf16(ka1, qf[d + 4], sb, 0, 0, 0);
    }
    __builtin_amdgcn_s_setprio(0);

    // softmax numerator: plain exp2 (no max: |logit| bounded tiny)
    f32x16 p0;
    float ls = 0.f;
#pragma unroll
    for (int r = 0; r < 16; ++r) {
      p0[r] = __builtin_amdgcn_exp2f(sa[r] + sb[r]);
      ls += p0[r];
    }
    lsum += ls;

    // pack P -> A-fragments in-register (T12)
    s16x8 pa[2];
    {
      u32 P2[8];
#pragma unroll
      for (int r = 0; r < 8; ++r)
        asm("v_cvt_pk_bf16_f32 %0, %1, %2"
            : "=v"(P2[r]) : "v"(p0[2 * r]), "v"(p0[2 * r + 1]));
#pragma unroll
      for (int b2 = 0; b2 < 2; ++b2) {
        u32 a0 = P2[b2 * 4 + 0], c0 = P2[b2 * 4 + 2];
        u32 a1 = P2[b2 * 4 + 1], c1 = P2[b2 * 4 + 3];
        asm("v_permlane32_swap_b32 %0, %1" : "+v"(a0), "+v"(c0));
        asm("v_permlane32_swap_b32 %0, %1" : "+v"(a1), "+v"(c1));
        union { u32 u[4]; s16x8 v; } pk;
        pk.u[0] = a0; pk.u[1] = a1; pk.u[2] = c0; pk.u[3] = c1;
        pa[b2] = pk.v;
      }
    }

    // PV: 4 independent 2-deep chains (dt), V from 256B-row LDS tiles
    __builtin_amdgcn_s_setprio(1);
#pragma unroll
    for (int ks = 0; ks < 2; ++ks) {
#pragma unroll
      for (int dt = 0; dt < 4; ++dt) {
        int rq = dt * 8 + (q32 >> 2);
        s16x8 vv = *(const s16x8*)(vb + rq * 256 +
            (((q32 & 3) * 64 + ks * 32 + hi * 16) ^ ((rq & 15) << 4)));
        o[dt] = __builtin_amdgcn_mfma_f32_32x32x16_bf16(pa[ks], vv, o[dt], 0, 0, 0);
      }
    }
    __builtin_amdgcn_s_setprio(0);
    __syncthreads();  // 4-wave dbuf handoff
  }

  // epilogue: packed bf16 partial O. Row slot = 128 u32; stream st at
  // u32[st*64 + 0..63]; slot q32 holds (d=q32, d=32+q32), slot 32+q32
  // holds (d=64+q32, d=96+q32).
  u32* Ob = OutU + st * 64;
#pragma unroll
  for (int r = 0; r < 16; ++r) {
    int qr = (r & 3) + 8 * (r >> 2) + 4 * hi;
    size_t rl = (size_t)(n * TDIM + qrow + qr) * 128;
    u32 a, bb;
    asm("v_cvt_pk_bf16_f32 %0, %1, %2" : "=v"(a) : "v"(o[0][r]), "v"(o[1][r]));
    asm("v_cvt_pk_bf16_f32 %0, %1, %2" : "=v"(bb) : "v"(o[2][r]), "v"(o[3][r]));
    Ob[rl + q32] = a;
    Ob[rl + 32 + q32] = bb;
  }
  Lp[(size_t)(n * TDIM + qrow + q32) * 4 + st * 2 + hi] = lsum;
}

// ---------------- kernel 3: merge packed partials + residual ----------------
// thread (row, pi): unpack 2 streams' bf16 pairs, /Σl, +H, write f32.
// Row's 64 threads are one wave -> lockstep loads precede stores (safe RMW).
__global__ __launch_bounds__(256) void merge_kernel(
    u32* __restrict__ OutU, const float* __restrict__ Lp,
    const float* __restrict__ H) {
  int gid = blockIdx.x * 256 + threadIdx.x;
  int row = gid >> 6;
  int pi = gid & 63;
  int q32 = pi & 31, k = pi >> 5;
  f32x4 la = *(const f32x4*)(Lp + (size_t)row * 4);
  float il = 1.0f / (la.x + la.y + la.z + la.w);
  size_t rb = (size_t)row * 128;
  u32 p0 = OutU[rb + pi], p1 = OutU[rb + 64 + pi];
#define BL(x) __builtin_bit_cast(float, (u32)((x) << 16))
#define BH(x) __builtin_bit_cast(float, (u32)((x) & 0xffff0000u))
  float slo = BL(p0) + BL(p1);
  float shi = BH(p0) + BH(p1);
#undef BL
#undef BH
  int d0 = k * 64 + q32, d1 = d0 + 32;
  float* Outf = (float*)OutU;
  Outf[rb + d0] = slo * il + H[rb + d0];
  Outf[rb + d1] = shi * il + H[rb + d1];
}

extern "C" void kernel_launch(void* const* d_in, const int* in_sizes, int n_in,
                              void* d_out, int out_size, void* d_ws, size_t ws_size,
                              hipStream_t stream) {
  const float* H  = (const float*)d_in[0];
  const float* Wq = (const float*)d_in[1];
  const float* bq = (const float*)d_in[2];
  const float* Wk = (const float*)d_in[3];
  const float* bk = (const float*)d_in[4];
  (void)bk;  // bk adds only a row-constant logit term (softmax-invariant)
  u32* OutU = (u32*)d_out;
  char* ws = (char*)d_ws;
  unsigned short* Mt = (unsigned short*)(ws);
  float* u = (float*)(ws + 32768);
  char* Qb = ws + 65536;
  char* Kb = Qb + 8388608;
  char* Vt = Kb + 8388608;
  float* Lp = (float*)(ws + 65536 + 3 * 8388608);  // 0.5MB

  prep_kernel<<<64, 256, 0, stream>>>(Wq, Wk, bq, Mt, u);
  proj_kernel<<<512, 256, 0, stream>>>(H, Mt, u, Qb, Kb, Vt);
  attn_kernel<<<512, 256, 0, stream>>>(Qb, Kb, Vt, OutU, Lp);
  merge_kernel<<<8192, 256, 0, stream>>>(OutU, Lp, H);
}